// Round 14
// baseline (156.744 us; speedup 1.0000x reference)
//
#include <hip/hip_runtime.h>
#include <hip/hip_fp16.h>

// ADI diffusion B=16, C=8, S=128, 10 steps. Round 23: r11 base (152.7us,
// proven best) + ONE change: the coef dispatch is deleted. The head now
// computes its own step-0 coefficients raw (coalesced bb/btc float2 for Y,
// ab/atc float4 for packed C -- both phases proven in r12's head2) and
// writes the packed __half2{g, rb-1} fields for steps 1..9 as a tail
// epilogue (proven in r12). stepS kernels are VERBATIM r11. 11->10
// dispatches. r13's bundled cuts (g-only, new head) regressed and are
// dropped.

constexpr int S_  = 128;
constexpr float EPSF = 1e-6f;
constexpr int CSS = 8 * 128 * 128;  // points per coeff field

// stepS LDS: 3 x 64 rows x 128 floats = 96 KB (r11)
constexpr int SA = 0;
constexpr int SB = 64 * 128;
constexpr int SC = 128 * 128;
constexpr int SPOOL = 192 * 128;
// head LDS: A @0 (64 rows), ST @96 (96 rows; B aliases its first 64), C @192
constexpr int HA  = 0;
constexpr int HST = 96 * 128;
constexpr int HB  = 96 * 128;
constexpr int HC  = 192 * 128;
constexpr int HPOOL = 256 * 128;    // 128 KB

__device__ __forceinline__ int swad4(int r, int b4) {
    return r * 128 + (((b4) ^ (r & 31)) << 2);
}
__device__ __forceinline__ int swadw(int r, int w) {
    return r * 128 + ((((w) >> 2) ^ (r & 31)) << 2) + ((w) & 3);
}

template <int N>
__device__ __forceinline__ void jrunN(const float (&e)[N], const float (&g)[N],
                                      float (&o)[N - 4]) {
    // Jacobi-2 == fixed 5-point formula, stencil radius 2 per output.
    float x1[N];
    #pragma unroll
    for (int i = 1; i <= N - 2; ++i) x1[i] = fmaf(g[i], e[i - 1] + e[i + 1], e[i]);
    #pragma unroll
    for (int i = 2; i <= N - 3; ++i) o[i - 2] = fmaf(g[i], x1[i - 1] + x1[i + 1], e[i]);
}

// gather 16 A-values + 16 packed-C words for run (r, wr)
#define TAPS_GATHER(RA, RC, f, cb)                                             \
    {                                                                          \
        _Pragma("unroll")                                                      \
        for (int i_ = 0; i_ < 4; ++i_) {                                       \
            const int bb_ = 2 * wr - 1 + i_;                                   \
            if (bb_ >= 0 && bb_ < 32) {                                        \
                const float4 va_ = *(const float4*)&sP[(RA) + swad4(r, bb_)];  \
                const float4 vc_ = *(const float4*)&sP[(RC) + swad4(r, bb_)];  \
                f[4*i_+0]=va_.x; f[4*i_+1]=va_.y; f[4*i_+2]=va_.z; f[4*i_+3]=va_.w; \
                cb[4*i_+0]=__float_as_uint(vc_.x); cb[4*i_+1]=__float_as_uint(vc_.y); \
                cb[4*i_+2]=__float_as_uint(vc_.z); cb[4*i_+3]=__float_as_uint(vc_.w); \
            } else {                                                           \
                f[4*i_+0]=f[4*i_+1]=f[4*i_+2]=f[4*i_+3]=0.f;                   \
                cb[4*i_+0]=cb[4*i_+1]=cb[4*i_+2]=cb[4*i_+3]=0u;                \
            }                                                                  \
        }                                                                      \
    }

// ---- head: step 0 with RAW coeffs + epilogue writing cf fields 1..9/11..19
__global__ __launch_bounds__(512) void head_kernel(
    const float* __restrict__ u0, __half* __restrict__ ud,
    const float* __restrict__ ab, const float* __restrict__ atc,
    const float* __restrict__ bb, const float* __restrict__ btc,
    const float* __restrict__ cm, __half2* __restrict__ cf)
{
    __shared__ __align__(16) float sP[HPOOL];
    const int tid = threadIdx.x;
    const int b   = blockIdx.x >> 4;
    const int h0  = (blockIdx.x & 15) << 3;
    const float dt2 = 0.0005f;

    // stage 96 rows (c*12+hh) x 32 b4 into ST; zeros outside domain
    #pragma unroll
    for (int m = 0; m < 6; ++m) {
        const int task = tid + 512 * m;
        const int r = task >> 5, b4 = task & 31;
        const int c = r / 12, hh = r - c * 12;
        const int gh = h0 - 2 + hh;
        float4 v = make_float4(0.f, 0.f, 0.f, 0.f);
        if (gh >= 0 && gh < S_) v = *(const float4*)&u0[((b * 8 + c) * S_ + gh) * S_ + 4 * b4];
        *(float4*)&sP[HST + swad4(r, b4)] = v;
    }
    __syncthreads();
    {   // mix0 in place on ST: 1536 pts, 3/thread
        float M[64];
        #pragma unroll
        for (int i = 0; i < 64; ++i) M[i] = cm[i];
        #pragma unroll
        for (int m = 0; m < 3; ++m) {
            const int p = tid + 512 * m;
            const int hh = p >> 7, w = p & 127;
            float v[8], o[8];
            #pragma unroll
            for (int c = 0; c < 8; ++c) v[c] = sP[HST + swadw(c * 12 + hh, w)];
            #pragma unroll
            for (int dd = 0; dd < 8; ++dd) {
                float a = 0.f;
                #pragma unroll
                for (int c = 0; c < 8; ++c) a = fmaf(M[dd * 8 + c], v[c], a);
                o[dd] = a;
            }
            #pragma unroll
            for (int c = 0; c < 8; ++c) sP[HST + swadw(c * 12 + hh, w)] = o[c];
        }
    }
    __syncthreads();
    {   // x@0 in place on ST: 96 rows x 16 runs, 3/thread; raw ab @ t=0
        float xh[3][8];
        #pragma unroll
        for (int m = 0; m < 3; ++m) {
            const int r  = (tid & 31) + 32 * m;
            const int wr = tid >> 5;
            const int w0 = wr * 8;
            const int c = r / 12, hh = r - c * 12;
            const int gh = h0 - 2 + hh;
            const bool rowin = (gh >= 0 && gh < S_);
            float f[16];
            #pragma unroll
            for (int i = 0; i < 4; ++i) {
                const int bb4 = 2 * wr - 1 + i;
                if (bb4 >= 0 && bb4 < 32) {
                    const float4 va = *(const float4*)&sP[HST + swad4(r, bb4)];
                    f[4*i+0]=va.x; f[4*i+1]=va.y; f[4*i+2]=va.z; f[4*i+3]=va.w;
                } else {
                    f[4*i+0]=f[4*i+1]=f[4*i+2]=f[4*i+3]=0.f;
                }
            }
            float e[12], g[12];
            #pragma unroll
            for (int j = 0; j < 12; ++j) {
                const int wj = w0 - 2 + j;
                const bool win = (wj >= 0 && wj < S_);
                float co = 0.f;
                if (rowin && win) {
                    float al = ab[(c * S_ + gh) * S_ + wj];
                    co = fminf(fmaxf(al, EPSF), 10.f) * 0.0005f;
                }
                const float nb = (wj == 0 || wj == S_ - 1) ? 1.f : 2.f;
                const float rb = __builtin_amdgcn_rcpf(fmaf(nb, co, 1.f) + EPSF);
                e[j] = rb * f[j + 2]; g[j] = rb * co;
            }
            jrunN<12>(e, g, xh[m]);
        }
        __syncthreads();
        #pragma unroll
        for (int m = 0; m < 3; ++m) {
            const int r  = (tid & 31) + 32 * m;
            const int wr = tid >> 5;
            *(float4*)&sP[HST + swad4(r, 2 * wr)]     = make_float4(xh[m][0], xh[m][1], xh[m][2], xh[m][3]);
            *(float4*)&sP[HST + swad4(r, 2 * wr + 1)] = make_float4(xh[m][4], xh[m][5], xh[m][6], xh[m][7]);
        }
    }
    __syncthreads();
    // Y raw @ t_y = 1*dt2: 12-in (ST) -> 8-out -> A
    {
        const int c = tid >> 6, wp = tid & 63, wb = 2 * wp;
        float2 dp[12], b2[12], t2[12];
        #pragma unroll
        for (int hh = 0; hh < 12; ++hh) {
            const int gh = h0 - 2 + hh;
            const bool inr = (gh >= 0 && gh < S_);
            const int ghc = inr ? gh : 0;
            const int r = c * 12 + hh;
            dp[hh] = *(const float2*)&sP[HST + r * 128 +
                                         (((wp >> 1) ^ (r & 31)) << 2) + 2 * (wp & 1)];
            b2[hh] = *(const float2*)&bb[(c * S_ + ghc) * S_ + wb];
            t2[hh] = *(const float2*)&btc[(c * S_ + ghc) * S_ + wb];
        }
        float o2[2][8];
        #pragma unroll
        for (int s = 0; s < 2; ++s) {
            float e[12], g[12];
            #pragma unroll
            for (int hh = 0; hh < 12; ++hh) {
                const int gh = h0 - 2 + hh;
                const bool inr = (gh >= 0 && gh < S_);
                float be = fmaf(s ? t2[hh].y : t2[hh].x, 1 * dt2, s ? b2[hh].y : b2[hh].x);
                be = fminf(fmaxf(be, EPSF), 10.f);
                const float co = inr ? be * 0.001f : 0.f;
                const float nb = (gh == 0 || gh == S_ - 1) ? 1.f : 2.f;
                const float rb = __builtin_amdgcn_rcpf(fmaf(nb, co, 1.f) + EPSF);
                e[hh] = rb * (s ? dp[hh].y : dp[hh].x);
                g[hh] = rb * co;
            }
            jrunN<12>(e, g, o2[s]);
        }
        #pragma unroll
        for (int i = 0; i < 8; ++i) {
            const int r = c * 8 + i;
            *(float2*)&sP[HA + r * 128 + (((wp >> 1) ^ (r & 31)) << 2) + 2 * (wp & 1)]
                = make_float2(o2[0][i], o2[1][i]);
        }
    }
    // C raw @ t_x = 2*dt2: 64 rows x 32 b4, 4/thread -> packed {g, rb-1}
    #pragma unroll
    for (int m = 0; m < 4; ++m) {
        const int task = tid + 512 * m;
        const int r = task >> 5, b4 = task & 31;
        const int c = r >> 3, ho = r & 7;
        const float4 a4 = *(const float4*)&ab[(c * S_ + h0 + ho) * S_ + 4 * b4];
        const float4 t4 = *(const float4*)&atc[(c * S_ + h0 + ho) * S_ + 4 * b4];
        uint pk[4];
        #pragma unroll
        for (int l = 0; l < 4; ++l) {
            const int w = 4 * b4 + l;
            const float av = l == 0 ? a4.x : (l == 1 ? a4.y : (l == 2 ? a4.z : a4.w));
            const float tv = l == 0 ? t4.x : (l == 1 ? t4.y : (l == 2 ? t4.z : t4.w));
            float al = fminf(fmaxf(fmaf(tv, 2 * dt2, av), EPSF), 10.f);
            const float co = al * 0.0005f;
            const float nb = (w == 0 || w == S_ - 1) ? 1.f : 2.f;
            const float rb = __builtin_amdgcn_rcpf(fmaf(nb, co, 1.f) + EPSF);
            __half2 hp = __floats2half2_rn(rb * co, rb - 1.f);
            pk[l] = *reinterpret_cast<uint*>(&hp);
        }
        *(float4*)&sP[HC + swad4(r, b4)] = make_float4(
            __uint_as_float(pk[0]), __uint_as_float(pk[1]),
            __uint_as_float(pk[2]), __uint_as_float(pk[3]));
    }
    __syncthreads();
    // X1: 64 rows x 16 runs, 2/thread; cache rb/g for X2
    float rbk[2][12], gk[2][12], xo[2][8];
    #pragma unroll
    for (int m = 0; m < 2; ++m) {
        const int r  = tid & 63;
        const int wr = (tid >> 6) + 8 * m;
        float f[16]; uint cb[16];
        TAPS_GATHER(HA, HC, f, cb)
        float e[12];
        #pragma unroll
        for (int j = 0; j < 12; ++j) {
            uint c_ = cb[j + 2];
            const float2 fc = __half22float2(*reinterpret_cast<__half2*>(&c_));
            rbk[m][j] = 1.f + fc.y; gk[m][j] = fc.x;
            e[j] = rbk[m][j] * f[j + 2];
        }
        jrunN<12>(e, gk[m], xo[m]);
    }
    // park xo -> HB (ST dead after Y)
    #pragma unroll
    for (int m = 0; m < 2; ++m) {
        const int r  = tid & 63;
        const int wr = (tid >> 6) + 8 * m;
        *(float4*)&sP[HB + swad4(r, 2 * wr)]     = make_float4(xo[m][0], xo[m][1], xo[m][2], xo[m][3]);
        *(float4*)&sP[HB + swad4(r, 2 * wr + 1)] = make_float4(xo[m][4], xo[m][5], xo[m][6], xo[m][7]);
    }
    __syncthreads();
    {   // mix: read HB, write HA: 1024 pts, 2/thread
        float M[64];
        #pragma unroll
        for (int i = 0; i < 64; ++i) M[i] = cm[i];
        #pragma unroll
        for (int m = 0; m < 2; ++m) {
            const int p = tid + 512 * m;
            const int ho = p >> 7, w = p & 127;
            float v[8], o[8];
            #pragma unroll
            for (int c = 0; c < 8; ++c) v[c] = sP[HB + swadw(c * 8 + ho, w)];
            #pragma unroll
            for (int dd = 0; dd < 8; ++dd) {
                float a = 0.f;
                #pragma unroll
                for (int c = 0; c < 8; ++c) a = fmaf(M[dd * 8 + c], v[c], a);
                o[dd] = a;
            }
            #pragma unroll
            for (int c = 0; c < 8; ++c) sP[HA + swadw(c * 8 + ho, w)] = o[c];
        }
    }
    __syncthreads();
    // X2: HA taps + cached coeffs -> fp16 out
    #pragma unroll
    for (int m = 0; m < 2; ++m) {
        const int r  = tid & 63;
        const int wr = (tid >> 6) + 8 * m;
        const int c = r >> 3, ho = r & 7;
        float f[16];
        #pragma unroll
        for (int i = 0; i < 4; ++i) {
            const int bb4 = 2 * wr - 1 + i;
            if (bb4 >= 0 && bb4 < 32) {
                const float4 va = *(const float4*)&sP[HA + swad4(r, bb4)];
                f[4*i+0]=va.x; f[4*i+1]=va.y; f[4*i+2]=va.z; f[4*i+3]=va.w;
            } else {
                f[4*i+0]=f[4*i+1]=f[4*i+2]=f[4*i+3]=0.f;
            }
        }
        float e[12];
        #pragma unroll
        for (int j = 0; j < 12; ++j) e[j] = rbk[m][j] * f[j + 2];
        float o[8]; jrunN<12>(e, gk[m], o);
        __half2 q0 = __floats2half2_rn(o[0], o[1]);
        __half2 q1 = __floats2half2_rn(o[2], o[3]);
        __half2 q2 = __floats2half2_rn(o[4], o[5]);
        __half2 q3 = __floats2half2_rn(o[6], o[7]);
        uint4 pk;
        pk.x = *reinterpret_cast<uint*>(&q0);
        pk.y = *reinterpret_cast<uint*>(&q1);
        pk.z = *reinterpret_cast<uint*>(&q2);
        pk.w = *reinterpret_cast<uint*>(&q3);
        *(uint4*)&ud[((b * 8 + c) * S_ + h0 + ho) * S_ + wr * 8] = pk;
    }

    // epilogue: packed coeff fields for steps 1..9 (1 pt/thread, coalesced)
    {
        const int idx = blockIdx.x * 512 + tid;
        const float abv = ab[idx], atv = atc[idx], bbv = bb[idx], btv = btc[idx];
        const int w = idx & 127, h = (idx >> 7) & 127;
        const float nbY = (h == 0 || h == S_ - 1) ? 1.f : 2.f;
        const float nbX = (w == 0 || w == S_ - 1) ? 1.f : 2.f;
        #pragma unroll
        for (int k = 1; k < 10; ++k) {
            float be = fminf(fmaxf(fmaf(btv, (2 * k + 1) * dt2, bbv), EPSF), 10.f);
            float co = be * 0.001f;
            float rb = __builtin_amdgcn_rcpf(fmaf(nbY, co, 1.f) + EPSF);
            cf[k * CSS + idx] = __floats2half2_rn(rb * co, rb - 1.f);
            float al = fminf(fmaxf(fmaf(atv, (2 * k + 2) * dt2, abv), EPSF), 10.f);
            co = al * 0.0005f;
            rb = __builtin_amdgcn_rcpf(fmaf(nbX, co, 1.f) + EPSF);
            cf[(10 + k) * CSS + idx] = __floats2half2_rn(rb * co, rb - 1.f);
        }
    }
}

// ---- mid/last step: VERBATIM r11 stepS ----
template <bool LASTK>
__global__ __launch_bounds__(512) void stepS_kernel(
    const __half* __restrict__ us, void* __restrict__ udst_,
    const __half2* __restrict__ cfy, const __half2* __restrict__ cfx,
    const float* __restrict__ cm)
{
    __shared__ __align__(16) float sP[SPOOL];
    const int tid = threadIdx.x;
    const int b   = blockIdx.x >> 4;
    const int h0  = (blockIdx.x & 15) << 3;

    // ---- Y: 512 col-pairs (c, w=2wp/2wp+1); 12-in -> 8-out -> A (swz)
    {
        const int c  = tid >> 6;
        const int wp = tid & 63;
        const int wbase = 2 * wp;
        uint du[12]; uint2 dc[12];
        #pragma unroll
        for (int hh = 0; hh < 12; ++hh) {
            const int gh = h0 - 2 + hh;
            const bool inr = (gh >= 0 && gh < S_);
            const int ghc = inr ? gh : 0;
            du[hh] = inr ? *(const uint*)&us[((b * 8 + c) * S_ + ghc) * S_ + wbase] : 0u;
            dc[hh] = *(const uint2*)&cfy[(c * S_ + ghc) * S_ + wbase];
        }
        float o2[2][8];
        #pragma unroll
        for (int s = 0; s < 2; ++s) {
            float e[12], g[12];
            #pragma unroll
            for (int hh = 0; hh < 12; ++hh) {
                const int gh = h0 - 2 + hh;
                const bool inr = (gh >= 0 && gh < S_);
                uint ub = du[hh];
                __half2 hu = *reinterpret_cast<__half2*>(&ub);
                const float dv = s ? __high2float(hu) : __low2float(hu);
                uint cb = s ? dc[hh].y : dc[hh].x;
                const float2 f = __half22float2(*reinterpret_cast<__half2*>(&cb));
                e[hh] = (1.f + f.y) * dv;
                g[hh] = inr ? f.x : 0.f;
            }
            jrunN<12>(e, g, o2[s]);
        }
        #pragma unroll
        for (int i = 0; i < 8; ++i) {
            const int r = c * 8 + i;
            *(float2*)&sP[SA + r * 128 + (((wp >> 1) ^ (r & 31)) << 2) + 2 * (wp & 1)]
                = make_float2(o2[0][i], o2[1][i]);
        }
    }
    // ---- C stage: 2048 tasks (64 rows x 32 blk4), 4/thread, uint4 -> b128
    {
        const uint* cfxu = (const uint*)cfx;
        #pragma unroll
        for (int m = 0; m < 4; ++m) {
            const int task = tid + 512 * m;
            const int r = task >> 5, col4 = task & 31;
            const int c = r >> 3, ho = r & 7;
            const uint4 v = *(const uint4*)&cfxu[(c * S_ + h0 + ho) * S_ + col4 * 4];
            *(float4*)&sP[SC + swad4(r, col4)] =
                make_float4(__uint_as_float(v.x), __uint_as_float(v.y),
                            __uint_as_float(v.z), __uint_as_float(v.w));
        }
    }
    __syncthreads();

    // ---- X1: 1024 runs, 2/thread; 4x b128 taps from A and C
    float rbk[2][12], gk[2][12], xo[2][8];
    #pragma unroll
    for (int m = 0; m < 2; ++m) {
        const int r  = tid & 63;
        const int wr = (tid >> 6) + 8 * m;      // wave-uniform
        float f[16]; uint cb[16];
        TAPS_GATHER(SA, SC, f, cb)
        float e[12];
        #pragma unroll
        for (int j = 0; j < 12; ++j) {
            uint c_ = cb[j + 2];
            const float2 fc = __half22float2(*reinterpret_cast<__half2*>(&c_));
            rbk[m][j] = 1.f + fc.y; gk[m][j] = fc.x;
            e[j] = rbk[m][j] * f[j + 2];
        }
        jrunN<12>(e, gk[m], xo[m]);
    }

    if (LASTK) {
        // final step: no mix; xo -> fp32 d_out
        float* ud = (float*)udst_;
        #pragma unroll
        for (int m = 0; m < 2; ++m) {
            const int r  = tid & 63;
            const int wr = (tid >> 6) + 8 * m;
            const int c = r >> 3, ho = r & 7;
            float4* dst4 = (float4*)&ud[((b * 8 + c) * S_ + h0 + ho) * S_ + wr * 8];
            dst4[0] = make_float4(xo[m][0], xo[m][1], xo[m][2], xo[m][3]);
            dst4[1] = make_float4(xo[m][4], xo[m][5], xo[m][6], xo[m][7]);
        }
    } else {
        // park xo -> B as 2x b128
        #pragma unroll
        for (int m = 0; m < 2; ++m) {
            const int r  = tid & 63;
            const int wr = (tid >> 6) + 8 * m;
            *(float4*)&sP[SB + swad4(r, 2 * wr)] =
                make_float4(xo[m][0], xo[m][1], xo[m][2], xo[m][3]);
            *(float4*)&sP[SB + swad4(r, 2 * wr + 1)] =
                make_float4(xo[m][4], xo[m][5], xo[m][6], xo[m][7]);
        }
        __syncthreads();
        {   // mix: 1024 pts, 2/thread; read B, write A (swz b32, conflict-free)
            float M[64];
            #pragma unroll
            for (int i = 0; i < 64; ++i) M[i] = cm[i];
            #pragma unroll
            for (int m = 0; m < 2; ++m) {
                const int p = tid + 512 * m;
                const int ho = p >> 7, w = p & 127;
                float v[8], o[8];
                #pragma unroll
                for (int c = 0; c < 8; ++c) {
                    const int r = c * 8 + ho;
                    v[c] = sP[SB + r * 128 + (((w >> 2) ^ (r & 31)) << 2) + (w & 3)];
                }
                #pragma unroll
                for (int dd = 0; dd < 8; ++dd) {
                    float a = 0.f;
                    #pragma unroll
                    for (int c = 0; c < 8; ++c) a = fmaf(M[dd * 8 + c], v[c], a);
                    o[dd] = a;
                }
                #pragma unroll
                for (int c = 0; c < 8; ++c) {
                    const int r = c * 8 + ho;
                    sP[SA + r * 128 + (((w >> 2) ^ (r & 31)) << 2) + (w & 3)] = o[c];
                }
            }
        }
        __syncthreads();
        // X2: re-read A (4x b128), reg-cached coeffs -> fp16 out (one b128 store)
        __half* ud = (__half*)udst_;
        #pragma unroll
        for (int m = 0; m < 2; ++m) {
            const int r  = tid & 63;
            const int wr = (tid >> 6) + 8 * m;
            const int c = r >> 3, ho = r & 7;
            float f[16];
            #pragma unroll
            for (int i = 0; i < 4; ++i) {
                const int bb = 2 * wr - 1 + i;
                if (bb >= 0 && bb < 32) {
                    const float4 va = *(const float4*)&sP[SA + swad4(r, bb)];
                    f[4 * i + 0] = va.x; f[4 * i + 1] = va.y;
                    f[4 * i + 2] = va.z; f[4 * i + 3] = va.w;
                } else {
                    f[4 * i + 0] = f[4 * i + 1] = f[4 * i + 2] = f[4 * i + 3] = 0.f;
                }
            }
            float e[12];
            #pragma unroll
            for (int j = 0; j < 12; ++j) e[j] = rbk[m][j] * f[j + 2];
            float o[8]; jrunN<12>(e, gk[m], o);
            __half2 q0 = __floats2half2_rn(o[0], o[1]);
            __half2 q1 = __floats2half2_rn(o[2], o[3]);
            __half2 q2 = __floats2half2_rn(o[4], o[5]);
            __half2 q3 = __floats2half2_rn(o[6], o[7]);
            uint4 pk;
            pk.x = *reinterpret_cast<uint*>(&q0);
            pk.y = *reinterpret_cast<uint*>(&q1);
            pk.z = *reinterpret_cast<uint*>(&q2);
            pk.w = *reinterpret_cast<uint*>(&q3);
            *(uint4*)&ud[((b * 8 + c) * S_ + h0 + ho) * S_ + wr * 8] = pk;
        }
    }
}

extern "C" void kernel_launch(void* const* d_in, const int* in_sizes, int n_in,
                              void* d_out, int out_size, void* d_ws, size_t ws_size,
                              hipStream_t stream) {
    const float* u_in = (const float*)d_in[0];
    const float* ab   = (const float*)d_in[1];
    const float* bbta = (const float*)d_in[2];
    const float* atc  = (const float*)d_in[3];
    const float* btc  = (const float*)d_in[4];
    const float* cm   = (const float*)d_in[5];
    float* uo = (float*)d_out;
    __half*  h1 = (__half*)d_ws;                                   // 4.2MB
    __half*  h2 = (__half*)((char*)d_ws + (8u << 20));             // 4.2MB
    __half2* cf = (__half2*)((char*)d_ws + (16u << 20));           // 10.5MB

    const dim3 g(256), blk(512);
    // head: step 0 (raw coeffs) -> h1 fp16, + writes cf fields 1..9 / 11..19
    head_kernel<<<g, blk, 0, stream>>>(u_in, h1, ab, atc, bbta, btc, cm, cf);
    const __half* s = h1; __half* d = h2;
    for (int k = 1; k <= 8; ++k) {
        stepS_kernel<false><<<g, blk, 0, stream>>>(s, d, cf + k * CSS,
                                                   cf + (10 + k) * CSS, cm);
        const __half* ns = d;
        d = (d == h2) ? h1 : h2;
        s = ns;
    }
    stepS_kernel<true><<<g, blk, 0, stream>>>(s, uo, cf + 9 * CSS,
                                              cf + 19 * CSS, cm);
}

// Round 15
// 153.970 us; speedup vs baseline: 1.0180x; 1.0180x over previous
//
#include <hip/hip_runtime.h>
#include <hip/hip_fp16.h>

// ADI diffusion B=16, C=8, S=128, 10 steps. Round 24: r11 restored verbatim
// (coef + head + launch; 152.7us proven best) + ONE zero-redundancy change
// in stepS: the SB park region is deleted. X1 parks back into SA after a
// barrier, mix runs IN PLACE on SA (each mix thread owns its 8 addresses),
// X2 reads SA. LDS 96KB -> 64KB => 2 blocks/CU (4 waves/SIMD, was 2) for
// +1 barrier and zero extra arithmetic. All prior occupancy tests bundled
// redundant work (r1 +33%, r8 +15%) and still showed -8% unit time; this
// isolates the occupancy effect cleanly. r13/r14 single-change regressions
// (g-only, head-fold) are dropped.

constexpr int S_  = 128;
constexpr int RS  = 129;            // head (unswizzled) LDS row stride
constexpr float EPSF = 1e-6f;
constexpr int CSS = 8 * 128 * 128;  // points per coeff field

// stepS swizzled LDS: 2 regions x 64 rows x 128 floats = 64 KB (was 96)
constexpr int SA = 0;
constexpr int SC = 64 * 128;
constexpr int SPOOL = 128 * 128;

__device__ __forceinline__ int swad4(int r, int b4) {
    return r * 128 + (((b4) ^ (r & 31)) << 2);
}

template <int N>
__device__ __forceinline__ void jrunN(const float (&e)[N], const float (&g)[N],
                                      float (&o)[N - 4]) {
    // Jacobi-2 == fixed 5-point formula, stencil radius 2 per output.
    float x1[N];
    #pragma unroll
    for (int i = 1; i <= N - 2; ++i) x1[i] = fmaf(g[i], e[i - 1] + e[i + 1], e[i]);
    #pragma unroll
    for (int i = 2; i <= N - 3; ++i) o[i - 2] = fmaf(g[i], x1[i - 1] + x1[i + 1], e[i]);
}

// ---- coefficient precompute (r9/r11, proven): fields 0..9 Y@t_y(k),
// 10..19 X@t_x(k), 20 X@t=0. Packed __half2{g = rb*co, rb-1}.
__global__ __launch_bounds__(256) void coef_kernel(
    const float* __restrict__ ab, const float* __restrict__ atc,
    const float* __restrict__ bb, const float* __restrict__ btc,
    __half2* __restrict__ cf)
{
    for (int gc = blockIdx.x * 256 + threadIdx.x; gc < CSS; gc += gridDim.x * 256) {
        const int w = gc & 127, h = (gc >> 7) & 127;
        const float abv = ab[gc], atv = atc[gc], bbv = bb[gc], btv = btc[gc];
        const float nbY = (h == 0 || h == S_ - 1) ? 1.f : 2.f;
        const float nbX = (w == 0 || w == S_ - 1) ? 1.f : 2.f;
        for (int k = 0; k < 10; ++k) {
            const float ty = (2 * k + 1) * 0.0005f;
            const float tx = (2 * k + 2) * 0.0005f;
            float be = fminf(fmaxf(fmaf(btv, ty, bbv), EPSF), 10.f);
            float co = be * 0.001f;
            float rb = __builtin_amdgcn_rcpf(fmaf(nbY, co, 1.f) + EPSF);
            cf[k * CSS + gc] = __floats2half2_rn(rb * co, rb - 1.f);
            float al = fminf(fmaxf(fmaf(atv, tx, abv), EPSF), 10.f);
            co = al * 0.0005f;
            rb = __builtin_amdgcn_rcpf(fmaf(nbX, co, 1.f) + EPSF);
            cf[(10 + k) * CSS + gc] = __floats2half2_rn(rb * co, rb - 1.f);
        }
        float al = fminf(fmaxf(abv, EPSF), 10.f);
        float co = al * 0.0005f;
        float rb = __builtin_amdgcn_rcpf(fmaf(nbX, co, 1.f) + EPSF);
        cf[20 * CSS + gc] = __floats2half2_rn(rb * co, rb - 1.f);
    }
}

// ---- head kernel: VERBATIM r11 (r9-style scalar-LDS step 0) ----
__global__ __launch_bounds__(512, 2) void head_kernel(
    const float* __restrict__ u0, __half* __restrict__ ud,
    const __half2* __restrict__ cfy, const __half2* __restrict__ cfx,
    const __half2* __restrict__ cfx0, const float* __restrict__ cm)
{
    constexpr int POOL   = 288 * RS;
    constexpr int OFF_A  = 0;
    constexpr int OFF_B  = 64 * RS;
    constexpr int OFF_CP = 192 * RS;
    constexpr int OFF_X0 = 96 * RS;
    __shared__ float sP[POOL];
    const int tid = threadIdx.x;
    const int b   = blockIdx.x >> 4;
    const int h0  = (blockIdx.x & 15) << 3;

    // stage 12-row pristine tile into ST=[0,96)
    #pragma unroll
    for (int m = 0; m < 2; ++m) {
        const int col = tid + 512 * m;
        const int c = col >> 7, w = col & 127;
        #pragma unroll
        for (int hh = 0; hh < 12; ++hh) {
            const int gh = h0 - 2 + hh;
            float v = 0.f;
            if (gh >= 0 && gh < S_) v = u0[((b * 8 + c) * S_ + gh) * S_ + w];
            sP[(c * 12 + hh) * RS + w] = v;
        }
    }
    // stage packed x@0 coeffs into [192,288)
    #pragma unroll
    for (int m = 0; m < 12; ++m) {
        const int task = tid + 512 * m;
        const int r = task >> 6, col2 = task & 63;
        const int c = r / 12, hh = r % 12;
        int gh = h0 - 2 + hh; gh = gh < 0 ? 0 : (gh >= S_ ? S_ - 1 : gh);
        const uint2 v = ((const uint2*)cfx0)[(c * S_ + gh) * 64 + col2];
        sP[OFF_CP + r * RS + col2 * 2]     = __uint_as_float(v.x);
        sP[OFF_CP + r * RS + col2 * 2 + 1] = __uint_as_float(v.y);
    }
    __syncthreads();
    {   // channel mix in place on ST
        float M[64];
        #pragma unroll
        for (int i = 0; i < 64; ++i) M[i] = cm[i];
        #pragma unroll
        for (int m = 0; m < 3; ++m) {
            const int p = tid + 512 * m;
            const int hh = p >> 7, w = p & 127;
            float v[8], o[8];
            #pragma unroll
            for (int c = 0; c < 8; ++c) v[c] = sP[(c * 12 + hh) * RS + w];
            #pragma unroll
            for (int dd = 0; dd < 8; ++dd) {
                float a = 0.f;
                #pragma unroll
                for (int c = 0; c < 8; ++c) a = fmaf(M[dd * 8 + c], v[c], a);
                o[dd] = a;
            }
            #pragma unroll
            for (int c = 0; c < 8; ++c) sP[(c * 12 + hh) * RS + w] = o[c];
        }
    }
    __syncthreads();
    // x@0: 96 rows x 16 runs, 3/thread -> X0
    #pragma unroll
    for (int m = 0; m < 3; ++m) {
        const int task = tid + 512 * m;
        const int r96 = task % 96, wr = task / 96;
        const int hh = r96 % 12;
        const int gh = h0 - 2 + hh;
        const bool rowin = (gh >= 0 && gh < S_);
        const int w0 = wr * 8;
        float e[12], g[12];
        #pragma unroll
        for (int j = 0; j < 12; ++j) {
            const int wj = w0 - 2 + j;
            const bool win = (wj >= 0 && wj < S_);
            const float dv = win ? sP[r96 * RS + wj] : 0.f;
            uint cb = (rowin && win) ? __float_as_uint(sP[OFF_CP + r96 * RS + wj]) : 0u;
            const float2 f = __half22float2(*reinterpret_cast<__half2*>(&cb));
            e[j] = (1.f + f.y) * dv;
            g[j] = f.x;
        }
        float o[8]; jrunN<12>(e, g, o);
        #pragma unroll
        for (int i = 0; i < 8; ++i) sP[OFF_X0 + r96 * RS + w0 + i] = o[i];
    }
    __syncthreads();

    // Y stage: reads X0; 12-in -> 8-out -> A
    #pragma unroll
    for (int m = 0; m < 2; ++m) {
        const int col = tid + 512 * m;
        const int c = col >> 7, w = col & 127;
        float e[12], g[12];
        #pragma unroll
        for (int hh = 0; hh < 12; ++hh) {
            const int gh = h0 - 2 + hh;
            const bool inr = (gh >= 0 && gh < S_);
            const int ghc = inr ? gh : 0;
            const float dv = sP[OFF_X0 + (c * 12 + hh) * RS + w];
            const float2 f = __half22float2(cfy[(c * S_ + ghc) * S_ + w]);
            e[hh] = (1.f + f.y) * dv;
            g[hh] = inr ? f.x : 0.f;
        }
        float o[8]; jrunN<12>(e, g, o);
        #pragma unroll
        for (int i = 0; i < 8; ++i) sP[OFF_A + (c * 8 + i) * RS + w] = o[i];
    }
    __syncthreads();
    // stage packed x-coeff into CP rows [0,64)
    #pragma unroll
    for (int m = 0; m < 8; ++m) {
        const int task = tid + 512 * m;
        const int r = task >> 6, col2 = task & 63;
        const int c = r >> 3, ho = r & 7;
        const uint2 v = ((const uint2*)cfx)[(c * S_ + h0 + ho) * 64 + col2];
        sP[OFF_CP + r * RS + col2 * 2]     = __uint_as_float(v.x);
        sP[OFF_CP + r * RS + col2 * 2 + 1] = __uint_as_float(v.y);
    }
    __syncthreads();

    // X1: 64 rows x 16 runs, 2/thread; cache rb/g for X2
    float rbk[2][12], gk[2][12], xo[2][8];
    #pragma unroll
    for (int m = 0; m < 2; ++m) {
        const int run = tid + 512 * m;
        const int r = run & 63, wr = run >> 6;
        const int w0 = wr * 8;
        float e[12];
        #pragma unroll
        for (int j = 0; j < 12; ++j) {
            const int wj = w0 - 2 + j;
            const bool win = (wj >= 0 && wj < S_);
            const float dv = win ? sP[OFF_A + r * RS + wj] : 0.f;
            uint cb = win ? __float_as_uint(sP[OFF_CP + r * RS + wj]) : 0u;
            const float2 f = __half22float2(*reinterpret_cast<__half2*>(&cb));
            rbk[m][j] = 1.f + f.y; gk[m][j] = f.x;
            e[j] = rbk[m][j] * dv;
        }
        jrunN<12>(e, gk[m], xo[m]);
    }
    // park xo -> B
    #pragma unroll
    for (int m = 0; m < 2; ++m) {
        const int run = tid + 512 * m;
        const int r = run & 63, w0 = (run >> 6) * 8;
        #pragma unroll
        for (int i = 0; i < 8; ++i) sP[OFF_B + r * RS + w0 + i] = xo[m][i];
    }
    __syncthreads();
    {   // mix: read B, write A
        float M[64];
        #pragma unroll
        for (int i = 0; i < 64; ++i) M[i] = cm[i];
        #pragma unroll
        for (int m = 0; m < 2; ++m) {
            const int p = tid + 512 * m;
            const int ho = p >> 7, w = p & 127;
            float v[8], o[8];
            #pragma unroll
            for (int c = 0; c < 8; ++c) v[c] = sP[OFF_B + (c * 8 + ho) * RS + w];
            #pragma unroll
            for (int dd = 0; dd < 8; ++dd) {
                float a = 0.f;
                #pragma unroll
                for (int c = 0; c < 8; ++c) a = fmaf(M[dd * 8 + c], v[c], a);
                o[dd] = a;
            }
            #pragma unroll
            for (int c = 0; c < 8; ++c) sP[OFF_A + (c * 8 + ho) * RS + w] = o[c];
        }
    }
    __syncthreads();
    // X2 -> fp16 out
    #pragma unroll
    for (int m = 0; m < 2; ++m) {
        const int run = tid + 512 * m;
        const int r = run & 63, wr = run >> 6;
        const int w0 = wr * 8;
        const int c = r >> 3, ho = r & 7;
        float e[12];
        #pragma unroll
        for (int j = 0; j < 12; ++j) {
            const int wj = w0 - 2 + j;
            const bool win = (wj >= 0 && wj < S_);
            const float dv = win ? sP[OFF_A + r * RS + wj] : 0.f;
            e[j] = rbk[m][j] * dv;
        }
        float o[8]; jrunN<12>(e, gk[m], o);
        __half2* d2 = (__half2*)&ud[((b * 8 + c) * S_ + h0 + ho) * S_ + w0];
        d2[0] = __floats2half2_rn(o[0], o[1]);
        d2[1] = __floats2half2_rn(o[2], o[3]);
        d2[2] = __floats2half2_rn(o[4], o[5]);
        d2[3] = __floats2half2_rn(o[6], o[7]);
    }
}

// ---- mid/last step: r11 stepS with SB deleted (in-place park+mix on SA) ----
template <bool LASTK>
__global__ __launch_bounds__(512, 4) void stepS_kernel(
    const __half* __restrict__ us, void* __restrict__ udst_,
    const __half2* __restrict__ cfy, const __half2* __restrict__ cfx,
    const float* __restrict__ cm)
{
    __shared__ __align__(16) float sP[SPOOL];
    const int tid = threadIdx.x;
    const int b   = blockIdx.x >> 4;
    const int h0  = (blockIdx.x & 15) << 3;

    // ---- Y: 512 col-pairs (c, w=2wp/2wp+1); 12-in -> 8-out -> A (swz)
    {
        const int c  = tid >> 6;
        const int wp = tid & 63;
        const int wbase = 2 * wp;
        uint du[12]; uint2 dc[12];
        #pragma unroll
        for (int hh = 0; hh < 12; ++hh) {
            const int gh = h0 - 2 + hh;
            const bool inr = (gh >= 0 && gh < S_);
            const int ghc = inr ? gh : 0;
            du[hh] = inr ? *(const uint*)&us[((b * 8 + c) * S_ + ghc) * S_ + wbase] : 0u;
            dc[hh] = *(const uint2*)&cfy[(c * S_ + ghc) * S_ + wbase];
        }
        float o2[2][8];
        #pragma unroll
        for (int s = 0; s < 2; ++s) {
            float e[12], g[12];
            #pragma unroll
            for (int hh = 0; hh < 12; ++hh) {
                const int gh = h0 - 2 + hh;
                const bool inr = (gh >= 0 && gh < S_);
                uint ub = du[hh];
                __half2 hu = *reinterpret_cast<__half2*>(&ub);
                const float dv = s ? __high2float(hu) : __low2float(hu);
                uint cb = s ? dc[hh].y : dc[hh].x;
                const float2 f = __half22float2(*reinterpret_cast<__half2*>(&cb));
                e[hh] = (1.f + f.y) * dv;
                g[hh] = inr ? f.x : 0.f;
            }
            jrunN<12>(e, g, o2[s]);
        }
        #pragma unroll
        for (int i = 0; i < 8; ++i) {
            const int r = c * 8 + i;
            *(float2*)&sP[SA + r * 128 + (((wp >> 1) ^ (r & 31)) << 2) + 2 * (wp & 1)]
                = make_float2(o2[0][i], o2[1][i]);
        }
    }
    // ---- C stage: 2048 tasks (64 rows x 32 blk4), 4/thread, uint4 -> b128
    {
        const uint* cfxu = (const uint*)cfx;
        #pragma unroll
        for (int m = 0; m < 4; ++m) {
            const int task = tid + 512 * m;
            const int r = task >> 5, col4 = task & 31;
            const int c = r >> 3, ho = r & 7;
            const uint4 v = *(const uint4*)&cfxu[(c * S_ + h0 + ho) * S_ + col4 * 4];
            *(float4*)&sP[SC + swad4(r, col4)] =
                make_float4(__uint_as_float(v.x), __uint_as_float(v.y),
                            __uint_as_float(v.z), __uint_as_float(v.w));
        }
    }
    __syncthreads();

    // ---- X1: 1024 runs, 2/thread; 4x b128 taps from A and C
    float rbk[2][12], gk[2][12], xo[2][8];
    #pragma unroll
    for (int m = 0; m < 2; ++m) {
        const int r  = tid & 63;
        const int wr = (tid >> 6) + 8 * m;      // wave-uniform
        float f[16]; uint cb[16];
        #pragma unroll
        for (int i = 0; i < 4; ++i) {
            const int bb = 2 * wr - 1 + i;
            if (bb >= 0 && bb < 32) {           // wave-uniform branch
                const float4 va = *(const float4*)&sP[SA + swad4(r, bb)];
                const float4 vc = *(const float4*)&sP[SC + swad4(r, bb)];
                f[4 * i + 0] = va.x; f[4 * i + 1] = va.y;
                f[4 * i + 2] = va.z; f[4 * i + 3] = va.w;
                cb[4 * i + 0] = __float_as_uint(vc.x);
                cb[4 * i + 1] = __float_as_uint(vc.y);
                cb[4 * i + 2] = __float_as_uint(vc.z);
                cb[4 * i + 3] = __float_as_uint(vc.w);
            } else {
                f[4 * i + 0] = f[4 * i + 1] = f[4 * i + 2] = f[4 * i + 3] = 0.f;
                cb[4 * i + 0] = cb[4 * i + 1] = cb[4 * i + 2] = cb[4 * i + 3] = 0u;
            }
        }
        float e[12];
        #pragma unroll
        for (int j = 0; j < 12; ++j) {
            uint c_ = cb[j + 2];
            const float2 fc = __half22float2(*reinterpret_cast<__half2*>(&c_));
            rbk[m][j] = 1.f + fc.y; gk[m][j] = fc.x;
            e[j] = rbk[m][j] * f[j + 2];
        }
        jrunN<12>(e, gk[m], xo[m]);
    }

    if (LASTK) {
        // final step: no mix; xo -> fp32 d_out
        float* ud = (float*)udst_;
        #pragma unroll
        for (int m = 0; m < 2; ++m) {
            const int r  = tid & 63;
            const int wr = (tid >> 6) + 8 * m;
            const int c = r >> 3, ho = r & 7;
            float4* dst4 = (float4*)&ud[((b * 8 + c) * S_ + h0 + ho) * S_ + wr * 8];
            dst4[0] = make_float4(xo[m][0], xo[m][1], xo[m][2], xo[m][3]);
            dst4[1] = make_float4(xo[m][4], xo[m][5], xo[m][6], xo[m][7]);
        }
    } else {
        __syncthreads();    // all X1 reads of SA complete before overwrite
        // park xo -> SA (in place of the old SB region)
        #pragma unroll
        for (int m = 0; m < 2; ++m) {
            const int r  = tid & 63;
            const int wr = (tid >> 6) + 8 * m;
            *(float4*)&sP[SA + swad4(r, 2 * wr)] =
                make_float4(xo[m][0], xo[m][1], xo[m][2], xo[m][3]);
            *(float4*)&sP[SA + swad4(r, 2 * wr + 1)] =
                make_float4(xo[m][4], xo[m][5], xo[m][6], xo[m][7]);
        }
        __syncthreads();
        {   // mix IN PLACE on SA: 1024 pts, 2/thread (each thread owns its 8 addrs)
            float M[64];
            #pragma unroll
            for (int i = 0; i < 64; ++i) M[i] = cm[i];
            #pragma unroll
            for (int m = 0; m < 2; ++m) {
                const int p = tid + 512 * m;
                const int ho = p >> 7, w = p & 127;
                float v[8], o[8];
                #pragma unroll
                for (int c = 0; c < 8; ++c) {
                    const int r = c * 8 + ho;
                    v[c] = sP[SA + r * 128 + (((w >> 2) ^ (r & 31)) << 2) + (w & 3)];
                }
                #pragma unroll
                for (int dd = 0; dd < 8; ++dd) {
                    float a = 0.f;
                    #pragma unroll
                    for (int c = 0; c < 8; ++c) a = fmaf(M[dd * 8 + c], v[c], a);
                    o[dd] = a;
                }
                #pragma unroll
                for (int c = 0; c < 8; ++c) {
                    const int r = c * 8 + ho;
                    sP[SA + r * 128 + (((w >> 2) ^ (r & 31)) << 2) + (w & 3)] = o[c];
                }
            }
        }
        __syncthreads();
        // X2: re-read SA (4x b128), reg-cached coeffs -> fp16 out
        __half* ud = (__half*)udst_;
        #pragma unroll
        for (int m = 0; m < 2; ++m) {
            const int r  = tid & 63;
            const int wr = (tid >> 6) + 8 * m;
            const int c = r >> 3, ho = r & 7;
            float f[16];
            #pragma unroll
            for (int i = 0; i < 4; ++i) {
                const int bb = 2 * wr - 1 + i;
                if (bb >= 0 && bb < 32) {
                    const float4 va = *(const float4*)&sP[SA + swad4(r, bb)];
                    f[4 * i + 0] = va.x; f[4 * i + 1] = va.y;
                    f[4 * i + 2] = va.z; f[4 * i + 3] = va.w;
                } else {
                    f[4 * i + 0] = f[4 * i + 1] = f[4 * i + 2] = f[4 * i + 3] = 0.f;
                }
            }
            float e[12];
            #pragma unroll
            for (int j = 0; j < 12; ++j) e[j] = rbk[m][j] * f[j + 2];
            float o[8]; jrunN<12>(e, gk[m], o);
            __half2 q0 = __floats2half2_rn(o[0], o[1]);
            __half2 q1 = __floats2half2_rn(o[2], o[3]);
            __half2 q2 = __floats2half2_rn(o[4], o[5]);
            __half2 q3 = __floats2half2_rn(o[6], o[7]);
            uint4 pk;
            pk.x = *reinterpret_cast<uint*>(&q0);
            pk.y = *reinterpret_cast<uint*>(&q1);
            pk.z = *reinterpret_cast<uint*>(&q2);
            pk.w = *reinterpret_cast<uint*>(&q3);
            *(uint4*)&ud[((b * 8 + c) * S_ + h0 + ho) * S_ + wr * 8] = pk;
        }
    }
}

extern "C" void kernel_launch(void* const* d_in, const int* in_sizes, int n_in,
                              void* d_out, int out_size, void* d_ws, size_t ws_size,
                              hipStream_t stream) {
    const float* u_in = (const float*)d_in[0];
    const float* ab   = (const float*)d_in[1];
    const float* bbta = (const float*)d_in[2];
    const float* atc  = (const float*)d_in[3];
    const float* btc  = (const float*)d_in[4];
    const float* cm   = (const float*)d_in[5];
    float* uo = (float*)d_out;
    __half*  h1 = (__half*)d_ws;                                   // 4.2MB
    __half*  h2 = (__half*)((char*)d_ws + (8u << 20));             // 4.2MB
    __half2* cf = (__half2*)((char*)d_ws + (16u << 20));           // 11MB

    coef_kernel<<<dim3(512), dim3(256), 0, stream>>>(ab, atc, bbta, btc, cf);

    const dim3 g(256), blk(512);
    head_kernel<<<g, blk, 0, stream>>>(u_in, h1, cf + 0 * CSS, cf + 10 * CSS,
                                       cf + 20 * CSS, cm);
    const __half* s = h1; __half* d = h2;
    for (int k = 1; k <= 8; ++k) {
        stepS_kernel<false><<<g, blk, 0, stream>>>(s, d, cf + k * CSS,
                                                   cf + (10 + k) * CSS, cm);
        const __half* ns = d;
        d = (d == h2) ? h1 : h2;
        s = ns;
    }
    stepS_kernel<true><<<g, blk, 0, stream>>>(s, uo, cf + 9 * CSS,
                                              cf + 19 * CSS, cm);
}